// Round 10
// baseline (236.802 us; speedup 1.0000x reference)
//
#include <hip/hip_runtime.h>

// Problem constants (fixed by the reference).
constexpr int N_NODES = 100000;
constexpr int N_EDGES = 1600000;
constexpr int IN_C  = 128;
constexpr int HID_C = 64;   // == OUT_C
constexpr int NUM_CLASSES = 40;

// Bucketed CSR build: 512-node buckets, fixed-capacity staging.
constexpr int BSH = 9;
constexpr int BUCK_N = 1 << BSH;                          // 512
constexpr int NBUCK = (N_NODES + BUCK_N - 1) >> BSH;      // 196
constexpr int BCAP = 9216;      // per-bucket cap; mean 8192, sd~90 (11σ margin)
constexpr int FS_EPT = 16;
constexpr int FS_T = 256;
constexpr int FS_CHUNK = FS_EPT * FS_T;                   // 4096
constexpr int FS_BLKS = (N_EDGES + FS_CHUNK - 1) / FS_CHUNK;  // 391

typedef __attribute__((ext_vector_type(8))) short bf16x8;
typedef __attribute__((ext_vector_type(4))) short short4v;
typedef __attribute__((ext_vector_type(4))) float f32x4;

// bf16 storage helpers (fp32 math everywhere; bf16 only at rest).
__device__ __forceinline__ unsigned short f2bf(float f) {
    unsigned u = __float_as_uint(f);
    return (unsigned short)((u + 0x7FFFu + ((u >> 16) & 1u)) >> 16);   // RNE
}
__device__ __forceinline__ float bf2f(unsigned short h) {
    return __uint_as_float((unsigned)h << 16);
}

// ---------------------------------------------------------------- CSR -------
// Group edges into fixed per-bucket staging regions, packed (src<<9)|dst_lo.
__global__ __launch_bounds__(FS_T) void fill_stage_kernel(
        const int* __restrict__ src, const int* __restrict__ dst,
        unsigned* __restrict__ gcur, unsigned* __restrict__ stage) {
    __shared__ unsigned hist[NBUCK];
    __shared__ unsigned rbase[NBUCK];
    int t = threadIdx.x;
    for (int i = t; i < NBUCK; i += FS_T) hist[i] = 0u;
    __syncthreads();
    int e0 = blockIdx.x * FS_CHUNK + t;
    unsigned pay[FS_EPT];
    unsigned br[FS_EPT];   // (bucket<<16)|rank
#pragma unroll
    for (int i = 0; i < FS_EPT; ++i) {
        int e = e0 + i * FS_T;
        br[i] = 0xFFFFFFFFu; pay[i] = 0u;
        if (e < N_EDGES) {
            unsigned d = (unsigned)dst[e];
            unsigned s = (unsigned)src[e];
            unsigned b = d >> BSH;
            unsigned r = atomicAdd(&hist[b], 1u);   // rank < 4096
            pay[i] = (s << BSH) | (d & (BUCK_N - 1u));
            br[i]  = (b << 16) | r;
        }
    }
    __syncthreads();
    for (int i = t; i < NBUCK; i += FS_T) {
        unsigned c = hist[i];
        rbase[i] = c ? ((unsigned)i * BCAP + atomicAdd(&gcur[i], c)) : 0u;
    }
    __syncthreads();
#pragma unroll
    for (int i = 0; i < FS_EPT; ++i) {
        if (br[i] != 0xFFFFFFFFu) {
            unsigned bb = br[i] >> 16;
            unsigned idx = rbase[bb] + (br[i] & 0xFFFFu);
            if (idx < (bb + 1u) * BCAP) stage[idx] = pay[i];   // safety clamp
        }
    }
}

// One block per bucket; 512 threads. Computes its own bucket base by
// scanning gcur (replaces the serializing 1-block scan_buckets dispatch).
__global__ __launch_bounds__(512) void fill_final_kernel(
        const unsigned* __restrict__ gcur,
        const unsigned* __restrict__ stage, unsigned* __restrict__ rowptr,
        float* __restrict__ inv, unsigned* __restrict__ csr_src) {
    __shared__ unsigned cur[BUCK_N];
    __shared__ unsigned ps[512];
    __shared__ unsigned buf[BCAP];
    int b = blockIdx.x, t = threadIdx.x;
    int lo = b << BSH;
    int nn = min(BUCK_N, N_NODES - lo);
    unsigned gv = (t < NBUCK) ? gcur[t] : 0u;
    ps[t] = gv;
    __syncthreads();
    for (int off = 1; off < 256; off <<= 1) {
        unsigned u = (t >= off) ? ps[t - off] : 0u;
        __syncthreads();
        ps[t] += u;
        __syncthreads();
    }
    unsigned base = ps[b] - gcur[b];          // exclusive prefix at b
    if (b == NBUCK - 1 && t == 0) rowptr[N_NODES] = ps[NBUCK - 1];
    unsigned c = min(gcur[b], (unsigned)BCAP);
    const unsigned* st = stage + (size_t)b * BCAP;
    cur[t] = 0u;
    __syncthreads();
    for (int i = t; i < (int)c; i += 512) atomicAdd(&cur[st[i] & (BUCK_N - 1u)], 1u);
    __syncthreads();
    unsigned d = cur[t];                      // in-bucket degree of node lo+t
    ps[t] = d;
    __syncthreads();
    for (int off = 1; off < 512; off <<= 1) {
        unsigned u = (t >= off) ? ps[t - off] : 0u;
        __syncthreads();
        ps[t] += u;
        __syncthreads();
    }
    unsigned off0 = ps[t] - d;   // exclusive prefix
    if (t < nn) {
        rowptr[lo + t] = base + off0;
        inv[lo + t] = rsqrtf((float)(d + 1u));
    }
    __syncthreads();
    cur[t] = off0;
    __syncthreads();
    for (int i = t; i < (int)c; i += 512) {
        unsigned v = st[i];
        unsigned pos = atomicAdd(&cur[v & (BUCK_N - 1u)], 1u);
        buf[pos] = v >> BSH;
    }
    __syncthreads();
    for (int i = t; i < (int)c; i += 512) csr_src[base + i] = buf[i];
}

// ----------------------------------------------- gather-aggregate helper ----
// Octet-per-node aggregation sums. Lane owns channels cl*8..cl*8+7.
// R9: explicit depth-8 software pipeline (R8 evidence: occupancy 39->58% but
// dur 45->42 -> wave count wasn't binding; per-wave dependent chain
// idx-load -> gather was). Chunks of 8: batch 8 index loads (one drain),
// then 8 independent gathers in flight, then accumulate. Same e order ->
// bit-identical numerics.
__device__ __forceinline__ void agg_sums(
        const unsigned* __restrict__ rowptr, const unsigned* __restrict__ csr_src,
        const uint4* __restrict__ hsrow, int node, int cl,
        float& a0, float& a1, float& a2, float& a3,
        float& a4, float& a5, float& a6, float& a7) {
    unsigned beg = rowptr[node], end = rowptr[node + 1];
    unsigned e = beg;
#define ACC8(v)                                   \
    a0 += __uint_as_float((v).x << 16);           \
    a1 += __uint_as_float((v).x & 0xFFFF0000u);   \
    a2 += __uint_as_float((v).y << 16);           \
    a3 += __uint_as_float((v).y & 0xFFFF0000u);   \
    a4 += __uint_as_float((v).z << 16);           \
    a5 += __uint_as_float((v).z & 0xFFFF0000u);   \
    a6 += __uint_as_float((v).w << 16);           \
    a7 += __uint_as_float((v).w & 0xFFFF0000u);
    while (e + 8 <= end) {
        unsigned s0 = csr_src[e + 0], s1 = csr_src[e + 1];
        unsigned s2 = csr_src[e + 2], s3 = csr_src[e + 3];
        unsigned s4 = csr_src[e + 4], s5 = csr_src[e + 5];
        unsigned s6 = csr_src[e + 6], s7 = csr_src[e + 7];
        uint4 v0 = hsrow[(size_t)s0 * 8 + cl];
        uint4 v1 = hsrow[(size_t)s1 * 8 + cl];
        uint4 v2 = hsrow[(size_t)s2 * 8 + cl];
        uint4 v3 = hsrow[(size_t)s3 * 8 + cl];
        uint4 v4 = hsrow[(size_t)s4 * 8 + cl];
        uint4 v5 = hsrow[(size_t)s5 * 8 + cl];
        uint4 v6 = hsrow[(size_t)s6 * 8 + cl];
        uint4 v7 = hsrow[(size_t)s7 * 8 + cl];
        ACC8(v0); ACC8(v1); ACC8(v2); ACC8(v3);
        ACC8(v4); ACC8(v5); ACC8(v6); ACC8(v7);
        e += 8;
    }
#pragma unroll 4
    for (; e < end; ++e) {
        unsigned s = csr_src[e];
        uint4 v = hsrow[(size_t)s * 8 + cl];
        ACC8(v);
    }
#undef ACC8
}

// ------------------------------------------- MFMA GEMM (X@W)*inv -> bf16 ----
// Layer-1 only (K=128, fp32 input). Verified layouts (§3).
__global__ __launch_bounds__(256) void gemm_mfma_kernel(
        const float* __restrict__ Xf, const float* __restrict__ W,
        const float* __restrict__ inv, unsigned short* __restrict__ out, int n) {
    constexpr int K = IN_C;
    __shared__ __align__(16) short Asd[64][K + 8];
    __shared__ __align__(16) short Bsd[64][K + 8];
    int t = threadIdx.x;
    int n0 = blockIdx.x * 64;
    for (int i = t; i < 64 * (K / 4); i += 256) {
        int row = i / (K / 4), seg = i % (K / 4);
        int node = n0 + row;
        float4 v = {0, 0, 0, 0};
        if (node < n) v = *(const float4*)&Xf[(size_t)node * K + seg * 4];
        short4v o;
        o.x = (short)f2bf(v.x); o.y = (short)f2bf(v.y);
        o.z = (short)f2bf(v.z); o.w = (short)f2bf(v.w);
        *(short4v*)&Asd[row][seg * 4] = o;
    }
    for (int i = t; i < K * 16; i += 256) {
        int k = i >> 4, ng = i & 15;
        float4 v = *(const float4*)&W[(size_t)k * 64 + ng * 4];
        Bsd[ng * 4 + 0][k] = (short)f2bf(v.x);
        Bsd[ng * 4 + 1][k] = (short)f2bf(v.y);
        Bsd[ng * 4 + 2][k] = (short)f2bf(v.z);
        Bsd[ng * 4 + 3][k] = (short)f2bf(v.w);
    }
    __syncthreads();
    int wv = t >> 6, lane = t & 63;
    int m = lane & 15, quad = lane >> 4;
    int rowbase = wv * 16;
    f32x4 acc0 = {0,0,0,0}, acc1 = {0,0,0,0}, acc2 = {0,0,0,0}, acc3 = {0,0,0,0};
#pragma unroll
    for (int kb = 0; kb < K / 32; ++kb) {
        bf16x8 af = *(const bf16x8*)&Asd[rowbase + m][kb * 32 + quad * 8];
        bf16x8 b0 = *(const bf16x8*)&Bsd[ 0 + m][kb * 32 + quad * 8];
        bf16x8 b1 = *(const bf16x8*)&Bsd[16 + m][kb * 32 + quad * 8];
        bf16x8 b2 = *(const bf16x8*)&Bsd[32 + m][kb * 32 + quad * 8];
        bf16x8 b3 = *(const bf16x8*)&Bsd[48 + m][kb * 32 + quad * 8];
        acc0 = __builtin_amdgcn_mfma_f32_16x16x32_bf16(af, b0, acc0, 0, 0, 0);
        acc1 = __builtin_amdgcn_mfma_f32_16x16x32_bf16(af, b1, acc1, 0, 0, 0);
        acc2 = __builtin_amdgcn_mfma_f32_16x16x32_bf16(af, b2, acc2, 0, 0, 0);
        acc3 = __builtin_amdgcn_mfma_f32_16x16x32_bf16(af, b3, acc3, 0, 0, 0);
    }
    f32x4 accs[4] = {acc0, acc1, acc2, acc3};
#pragma unroll
    for (int r = 0; r < 4; ++r) {
        int node = n0 + rowbase + quad * 4 + r;
        if (node < n) {
            float sc = inv[node];
#pragma unroll
            for (int s = 0; s < 4; ++s)
                out[(size_t)node * 64 + s * 16 + m] = f2bf(accs[s][r] * sc);
        }
    }
}

// -------------------------- FUSED: aggregate(h1) + ReLU + (h@W2)*inv -> B ---
// 512 threads; single-pass gather: 8 waves x 8 octets = 64 nodes.
// MFMA phase: wave w -> row-tile (w&3), col-half (w>>2) of the 64x64 output.
__global__ __launch_bounds__(512) void agg_gemm2_kernel(
        const unsigned* __restrict__ rowptr, const unsigned* __restrict__ csr_src,
        const unsigned short* __restrict__ hs, const float* __restrict__ inv,
        const float* __restrict__ bias, const float* __restrict__ W,
        unsigned short* __restrict__ out, int n) {
    constexpr int K = HID_C;   // 64
    __shared__ __align__(16) short Asd[64][K + 8];
    __shared__ __align__(16) short Bsd[64][K + 8];
    int t = threadIdx.x;
    int n0 = blockIdx.x * 64;
    int lane = t & 63, w = t >> 6;
    int oct = lane >> 3, cl = lane & 7;
    const uint4* hsrow = (const uint4*)hs;
    // stage W2^T -> Bsd
    for (int i = t; i < K * 16; i += 512) {
        int k = i >> 4, ng = i & 15;
        float4 v = *(const float4*)&W[(size_t)k * 64 + ng * 4];
        Bsd[ng * 4 + 0][k] = (short)f2bf(v.x);
        Bsd[ng * 4 + 1][k] = (short)f2bf(v.y);
        Bsd[ng * 4 + 2][k] = (short)f2bf(v.z);
        Bsd[ng * 4 + 3][k] = (short)f2bf(v.w);
    }
    // phase 1: aggregate + ReLU -> Asd (single pass, node nl = w*8+oct)
    float4 bv0 = *(const float4*)&bias[cl * 8];
    float4 bv1 = *(const float4*)&bias[cl * 8 + 4];
    {
        int nl = w * 8 + oct;
        int node = n0 + nl;
        float r0 = 0.f, r1 = 0.f, r2 = 0.f, r3 = 0.f;
        float r4 = 0.f, r5 = 0.f, r6 = 0.f, r7 = 0.f;
        if (node < n) {
            float a0 = 0.f, a1 = 0.f, a2 = 0.f, a3 = 0.f;
            float a4 = 0.f, a5 = 0.f, a6 = 0.f, a7 = 0.f;
            agg_sums(rowptr, csr_src, hsrow, node, cl, a0, a1, a2, a3, a4, a5, a6, a7);
            uint4 sv = hsrow[(size_t)node * 8 + cl];
            float s = inv[node];
            r0 = fmaxf(s * (a0 + __uint_as_float(sv.x << 16))         + bv0.x, 0.f);
            r1 = fmaxf(s * (a1 + __uint_as_float(sv.x & 0xFFFF0000u)) + bv0.y, 0.f);
            r2 = fmaxf(s * (a2 + __uint_as_float(sv.y << 16))         + bv0.z, 0.f);
            r3 = fmaxf(s * (a3 + __uint_as_float(sv.y & 0xFFFF0000u)) + bv0.w, 0.f);
            r4 = fmaxf(s * (a4 + __uint_as_float(sv.z << 16))         + bv1.x, 0.f);
            r5 = fmaxf(s * (a5 + __uint_as_float(sv.z & 0xFFFF0000u)) + bv1.y, 0.f);
            r6 = fmaxf(s * (a6 + __uint_as_float(sv.w << 16))         + bv1.z, 0.f);
            r7 = fmaxf(s * (a7 + __uint_as_float(sv.w & 0xFFFF0000u)) + bv1.w, 0.f);
        }
        uint4 o;
        o.x = (unsigned)f2bf(r0) | ((unsigned)f2bf(r1) << 16);
        o.y = (unsigned)f2bf(r2) | ((unsigned)f2bf(r3) << 16);
        o.z = (unsigned)f2bf(r4) | ((unsigned)f2bf(r5) << 16);
        o.w = (unsigned)f2bf(r6) | ((unsigned)f2bf(r7) << 16);
        *(uint4*)&Asd[nl][cl * 8] = o;
    }
    __syncthreads();
    // phase 2: K=64 MFMA GEMM from LDS; wave w -> rows (w&3)*16, cols (w>>2)*32
    int m = lane & 15, quad = lane >> 4;
    int rowbase = (w & 3) * 16;
    int ch = w >> 2;   // column half: 0 or 1
    f32x4 acc0 = {0,0,0,0}, acc1 = {0,0,0,0};
#pragma unroll
    for (int kb = 0; kb < K / 32; ++kb) {
        bf16x8 af = *(const bf16x8*)&Asd[rowbase + m][kb * 32 + quad * 8];
        bf16x8 b0 = *(const bf16x8*)&Bsd[ch * 32 +  0 + m][kb * 32 + quad * 8];
        bf16x8 b1 = *(const bf16x8*)&Bsd[ch * 32 + 16 + m][kb * 32 + quad * 8];
        acc0 = __builtin_amdgcn_mfma_f32_16x16x32_bf16(af, b0, acc0, 0, 0, 0);
        acc1 = __builtin_amdgcn_mfma_f32_16x16x32_bf16(af, b1, acc1, 0, 0, 0);
    }
    f32x4 accs[2] = {acc0, acc1};
#pragma unroll
    for (int r = 0; r < 4; ++r) {
        int node = n0 + rowbase + quad * 4 + r;
        if (node < n) {
            float sc = inv[node];
#pragma unroll
            for (int s = 0; s < 2; ++s)
                out[(size_t)node * 64 + ch * 32 + s * 16 + m] = f2bf(accs[s][r] * sc);
        }
    }
}

// ------------------- FUSED: aggregate(h2) + ReLU + classifier @Wf -> out ----
// 512 threads, single-pass gather. MFMA classifier: waves 0-3 -> col-tiles
// 0,1; waves 4-7 -> col-tile 2.
__global__ __launch_bounds__(512) void agg_final_kernel(
        const unsigned* __restrict__ rowptr, const unsigned* __restrict__ csr_src,
        const unsigned short* __restrict__ hs, const float* __restrict__ inv,
        const float* __restrict__ bias, const float* __restrict__ Wf,
        const float* __restrict__ bfv, float* __restrict__ out, int n) {
    constexpr int K = HID_C;         // 64
    constexpr int J = NUM_CLASSES;   // 40
    __shared__ __align__(16) short Asd[64][K + 8];
    __shared__ __align__(16) short Bwf[48][K + 8];
    int t = threadIdx.x;
    int n0 = blockIdx.x * 64;
    int lane = t & 63, w = t >> 6;
    int oct = lane >> 3, cl = lane & 7;
    const uint4* hsrow = (const uint4*)hs;
    // stage Wf^T -> Bwf (class-major, k-contiguous); zero pad rows 40..47
    for (int i = t; i < 48 * K; i += 512) {
        int j = i >> 6, k = i & 63;
        Bwf[j][k] = (j < J) ? (short)f2bf(Wf[(size_t)k * J + j]) : (short)0;
    }
    // phase 1: aggregate + ReLU -> Asd (bf16), single pass
    float4 bv0 = *(const float4*)&bias[cl * 8];
    float4 bv1 = *(const float4*)&bias[cl * 8 + 4];
    {
        int nl = w * 8 + oct;
        int node = n0 + nl;
        float r0 = 0.f, r1 = 0.f, r2 = 0.f, r3 = 0.f;
        float r4 = 0.f, r5 = 0.f, r6 = 0.f, r7 = 0.f;
        if (node < n) {
            float a0 = 0.f, a1 = 0.f, a2 = 0.f, a3 = 0.f;
            float a4 = 0.f, a5 = 0.f, a6 = 0.f, a7 = 0.f;
            agg_sums(rowptr, csr_src, hsrow, node, cl, a0, a1, a2, a3, a4, a5, a6, a7);
            uint4 sv = hsrow[(size_t)node * 8 + cl];
            float s = inv[node];
            r0 = fmaxf(s * (a0 + __uint_as_float(sv.x << 16))         + bv0.x, 0.f);
            r1 = fmaxf(s * (a1 + __uint_as_float(sv.x & 0xFFFF0000u)) + bv0.y, 0.f);
            r2 = fmaxf(s * (a2 + __uint_as_float(sv.y << 16))         + bv0.z, 0.f);
            r3 = fmaxf(s * (a3 + __uint_as_float(sv.y & 0xFFFF0000u)) + bv0.w, 0.f);
            r4 = fmaxf(s * (a4 + __uint_as_float(sv.z << 16))         + bv1.x, 0.f);
            r5 = fmaxf(s * (a5 + __uint_as_float(sv.z & 0xFFFF0000u)) + bv1.y, 0.f);
            r6 = fmaxf(s * (a6 + __uint_as_float(sv.w << 16))         + bv1.z, 0.f);
            r7 = fmaxf(s * (a7 + __uint_as_float(sv.w & 0xFFFF0000u)) + bv1.w, 0.f);
        }
        uint4 o;
        o.x = (unsigned)f2bf(r0) | ((unsigned)f2bf(r1) << 16);
        o.y = (unsigned)f2bf(r2) | ((unsigned)f2bf(r3) << 16);
        o.z = (unsigned)f2bf(r4) | ((unsigned)f2bf(r5) << 16);
        o.w = (unsigned)f2bf(r6) | ((unsigned)f2bf(r7) << 16);
        *(uint4*)&Asd[nl][cl * 8] = o;
    }
    __syncthreads();
    // phase 2: MFMA classifier; waves 0-3: col-tiles 0,1; waves 4-7: tile 2
    int m = lane & 15, quad = lane >> 4;
    int rowbase = (w & 3) * 16;
    if (w < 4) {
        f32x4 acc0 = {0,0,0,0}, acc1 = {0,0,0,0};
#pragma unroll
        for (int kb = 0; kb < K / 32; ++kb) {
            bf16x8 af = *(const bf16x8*)&Asd[rowbase + m][kb * 32 + quad * 8];
            bf16x8 b0 = *(const bf16x8*)&Bwf[ 0 + m][kb * 32 + quad * 8];
            bf16x8 b1 = *(const bf16x8*)&Bwf[16 + m][kb * 32 + quad * 8];
            acc0 = __builtin_amdgcn_mfma_f32_16x16x32_bf16(af, b0, acc0, 0, 0, 0);
            acc1 = __builtin_amdgcn_mfma_f32_16x16x32_bf16(af, b1, acc1, 0, 0, 0);
        }
        f32x4 accs[2] = {acc0, acc1};
#pragma unroll
        for (int r = 0; r < 4; ++r) {
            int node = n0 + rowbase + quad * 4 + r;
            if (node < n) {
#pragma unroll
                for (int s = 0; s < 2; ++s) {
                    int col = s * 16 + m;
                    out[(size_t)node * J + col] = accs[s][r] + bfv[col];
                }
            }
        }
    } else {
        f32x4 acc2 = {0,0,0,0};
#pragma unroll
        for (int kb = 0; kb < K / 32; ++kb) {
            bf16x8 af = *(const bf16x8*)&Asd[rowbase + m][kb * 32 + quad * 8];
            bf16x8 b2 = *(const bf16x8*)&Bwf[32 + m][kb * 32 + quad * 8];
            acc2 = __builtin_amdgcn_mfma_f32_16x16x32_bf16(af, b2, acc2, 0, 0, 0);
        }
#pragma unroll
        for (int r = 0; r < 4; ++r) {
            int node = n0 + rowbase + quad * 4 + r;
            if (node < n) {
                int col = 32 + m;
                if (col < J)
                    out[(size_t)node * J + col] = acc2[r] + bfv[col];
            }
        }
    }
}

// ---------------------------------------------------------------- launch ----
extern "C" void kernel_launch(void* const* d_in, const int* in_sizes, int n_in,
                              void* d_out, int out_size, void* d_ws, size_t ws_size,
                              hipStream_t stream) {
    const float* x  = (const float*)d_in[0];
    const int*   ei = (const int*)d_in[1];
    const float* W1 = (const float*)d_in[2];
    const float* b1 = (const float*)d_in[3];
    const float* W2 = (const float*)d_in[4];
    const float* b2 = (const float*)d_in[5];
    const float* Wf = (const float*)d_in[6];
    const float* bf = (const float*)d_in[7];
    float* out = (float*)d_out;

    const int* src = ei;            // edge_index[0, :]
    const int* dst = ei + N_EDGES;  // edge_index[1, :]

    // Workspace layout (bytes):
    // rowptr: [0, 400064) | inv: [400064, 800064) | gcur: [800064, 800896)
    // csr_src: [801792, 7201792)
    // A (bf16, 12.8MB): [7201792, 20001792) | B (bf16): [20001792, 32801792)
    // stage (7.23 MB) aliases A: dead before gemm1 writes A (stream-ordered).
    char* ws = (char*)d_ws;
    unsigned* rowptr  = (unsigned*)(ws + 0);
    float*    inv     = (float*)   (ws + 400064);
    unsigned* gcur    = (unsigned*)(ws + 800064);
    unsigned* csr_src = (unsigned*)(ws + 801792);
    unsigned short* A = (unsigned short*)(ws + 7201792);
    unsigned short* B = (unsigned short*)(ws + 20001792);
    unsigned* stage   = (unsigned*)A;

    // ---- CSR build (per-call; no state survives between calls)
    hipMemsetAsync(gcur, 0, NBUCK * sizeof(unsigned), stream);
    fill_stage_kernel<<<FS_BLKS, FS_T, 0, stream>>>(src, dst, gcur, stage);
    fill_final_kernel<<<NBUCK, 512, 0, stream>>>(gcur, stage, rowptr, inv, csr_src);

    // ---- Layer 1 GEMM: A = (x@W1)*inv (bf16)
    gemm_mfma_kernel<<<(N_NODES + 63) / 64, 256, 0, stream>>>(x, W1, inv, A, N_NODES);

    // ---- Fused: h1 = ReLU(agg(A)+b1); B = (h1@W2)*inv
    agg_gemm2_kernel<<<(N_NODES + 63) / 64, 512, 0, stream>>>(
        rowptr, csr_src, A, inv, b1, W2, B, N_NODES);

    // ---- Fused: h2 = ReLU(agg(B)+b2); out = h2@Wf + bf
    agg_final_kernel<<<(N_NODES + 63) / 64, 512, 0, stream>>>(
        rowptr, csr_src, B, inv, b2, Wf, bf, out, N_NODES);
}

// Round 11
// 225.333 us; speedup vs baseline: 1.0509x; 1.0509x over previous
//
#include <hip/hip_runtime.h>

// Problem constants (fixed by the reference).
constexpr int N_NODES = 100000;
constexpr int N_EDGES = 1600000;
constexpr int IN_C  = 128;
constexpr int HID_C = 64;   // == OUT_C
constexpr int NUM_CLASSES = 40;

// Bucketed CSR build: 512-node buckets, fixed-capacity staging.
constexpr int BSH = 9;
constexpr int BUCK_N = 1 << BSH;                          // 512
constexpr int NBUCK = (N_NODES + BUCK_N - 1) >> BSH;      // 196
constexpr int BCAP = 9216;      // per-bucket cap; mean 8192, sd~90 (11σ margin)
constexpr int FS_EPT = 16;
constexpr int FS_T = 256;
constexpr int FS_CHUNK = FS_EPT * FS_T;                   // 4096
constexpr int FS_BLKS = (N_EDGES + FS_CHUNK - 1) / FS_CHUNK;  // 391

typedef __attribute__((ext_vector_type(8))) short bf16x8;
typedef __attribute__((ext_vector_type(4))) short short4v;
typedef __attribute__((ext_vector_type(4))) float f32x4;

// bf16 storage helpers (fp32 math everywhere; bf16 only at rest).
__device__ __forceinline__ unsigned short f2bf(float f) {
    unsigned u = __float_as_uint(f);
    return (unsigned short)((u + 0x7FFFu + ((u >> 16) & 1u)) >> 16);   // RNE
}
__device__ __forceinline__ float bf2f(unsigned short h) {
    return __uint_as_float((unsigned)h << 16);
}

// ---------------------------------------------------------------- CSR -------
// Group edges into fixed per-bucket staging regions, packed (src<<9)|dst_lo.
__global__ __launch_bounds__(FS_T) void fill_stage_kernel(
        const int* __restrict__ src, const int* __restrict__ dst,
        unsigned* __restrict__ gcur, unsigned* __restrict__ stage) {
    __shared__ unsigned hist[NBUCK];
    __shared__ unsigned rbase[NBUCK];
    int t = threadIdx.x;
    for (int i = t; i < NBUCK; i += FS_T) hist[i] = 0u;
    __syncthreads();
    int e0 = blockIdx.x * FS_CHUNK + t;
    unsigned pay[FS_EPT];
    unsigned br[FS_EPT];   // (bucket<<16)|rank
#pragma unroll
    for (int i = 0; i < FS_EPT; ++i) {
        int e = e0 + i * FS_T;
        br[i] = 0xFFFFFFFFu; pay[i] = 0u;
        if (e < N_EDGES) {
            unsigned d = (unsigned)dst[e];
            unsigned s = (unsigned)src[e];
            unsigned b = d >> BSH;
            unsigned r = atomicAdd(&hist[b], 1u);   // rank < 4096
            pay[i] = (s << BSH) | (d & (BUCK_N - 1u));
            br[i]  = (b << 16) | r;
        }
    }
    __syncthreads();
    for (int i = t; i < NBUCK; i += FS_T) {
        unsigned c = hist[i];
        rbase[i] = c ? ((unsigned)i * BCAP + atomicAdd(&gcur[i], c)) : 0u;
    }
    __syncthreads();
#pragma unroll
    for (int i = 0; i < FS_EPT; ++i) {
        if (br[i] != 0xFFFFFFFFu) {
            unsigned bb = br[i] >> 16;
            unsigned idx = rbase[bb] + (br[i] & 0xFFFFu);
            if (idx < (bb + 1u) * BCAP) stage[idx] = pay[i];   // safety clamp
        }
    }
}

// One block per bucket; 512 threads. Computes its own bucket base by
// scanning gcur (replaces the serializing 1-block scan_buckets dispatch).
__global__ __launch_bounds__(512) void fill_final_kernel(
        const unsigned* __restrict__ gcur,
        const unsigned* __restrict__ stage, unsigned* __restrict__ rowptr,
        float* __restrict__ inv, unsigned* __restrict__ csr_src) {
    __shared__ unsigned cur[BUCK_N];
    __shared__ unsigned ps[512];
    __shared__ unsigned buf[BCAP];
    int b = blockIdx.x, t = threadIdx.x;
    int lo = b << BSH;
    int nn = min(BUCK_N, N_NODES - lo);
    unsigned gv = (t < NBUCK) ? gcur[t] : 0u;
    ps[t] = gv;
    __syncthreads();
    for (int off = 1; off < 256; off <<= 1) {
        unsigned u = (t >= off) ? ps[t - off] : 0u;
        __syncthreads();
        ps[t] += u;
        __syncthreads();
    }
    unsigned base = ps[b] - gcur[b];          // exclusive prefix at b
    if (b == NBUCK - 1 && t == 0) rowptr[N_NODES] = ps[NBUCK - 1];
    unsigned c = min(gcur[b], (unsigned)BCAP);
    const unsigned* st = stage + (size_t)b * BCAP;
    cur[t] = 0u;
    __syncthreads();
    for (int i = t; i < (int)c; i += 512) atomicAdd(&cur[st[i] & (BUCK_N - 1u)], 1u);
    __syncthreads();
    unsigned d = cur[t];                      // in-bucket degree of node lo+t
    ps[t] = d;
    __syncthreads();
    for (int off = 1; off < 512; off <<= 1) {
        unsigned u = (t >= off) ? ps[t - off] : 0u;
        __syncthreads();
        ps[t] += u;
        __syncthreads();
    }
    unsigned off0 = ps[t] - d;   // exclusive prefix
    if (t < nn) {
        rowptr[lo + t] = base + off0;
        inv[lo + t] = rsqrtf((float)(d + 1u));
    }
    __syncthreads();
    cur[t] = off0;
    __syncthreads();
    for (int i = t; i < (int)c; i += 512) {
        unsigned v = st[i];
        unsigned pos = atomicAdd(&cur[v & (BUCK_N - 1u)], 1u);
        buf[pos] = v >> BSH;
    }
    __syncthreads();
    for (int i = t; i < (int)c; i += 512) csr_src[base + i] = buf[i];
}

// ----------------------------------------------- gather-aggregate helper ----
// Octet-per-node aggregation sums. Lane owns channels cl*8..cl*8+7; index
// load is octet-uniform -> broadcast. R10: reverted to the R8 rolled form
// (unroll 4). Ledger: R9's explicit depth-8 batch REGRESSED (+9.6 us; single
// coarse vmcnt drain beat the compiler's finer interleave; occupancy 58->33).
__device__ __forceinline__ void agg_sums(
        const unsigned* __restrict__ rowptr, const unsigned* __restrict__ csr_src,
        const uint4* __restrict__ hsrow, int node, int cl,
        float& a0, float& a1, float& a2, float& a3,
        float& a4, float& a5, float& a6, float& a7) {
    unsigned beg = rowptr[node], end = rowptr[node + 1];
#pragma unroll 4
    for (unsigned e = beg; e < end; ++e) {
        unsigned s = csr_src[e];
        uint4 v = hsrow[(size_t)s * 8 + cl];
        a0 += __uint_as_float(v.x << 16);
        a1 += __uint_as_float(v.x & 0xFFFF0000u);
        a2 += __uint_as_float(v.y << 16);
        a3 += __uint_as_float(v.y & 0xFFFF0000u);
        a4 += __uint_as_float(v.z << 16);
        a5 += __uint_as_float(v.z & 0xFFFF0000u);
        a6 += __uint_as_float(v.w << 16);
        a7 += __uint_as_float(v.w & 0xFFFF0000u);
    }
}

// ------------------------------------------- MFMA GEMM (X@W)*inv -> bf16 ----
// Layer-1 only (K=128, fp32 input). Verified layouts (§3).
__global__ __launch_bounds__(256) void gemm_mfma_kernel(
        const float* __restrict__ Xf, const float* __restrict__ W,
        const float* __restrict__ inv, unsigned short* __restrict__ out, int n) {
    constexpr int K = IN_C;
    __shared__ __align__(16) short Asd[64][K + 8];
    __shared__ __align__(16) short Bsd[64][K + 8];
    int t = threadIdx.x;
    int n0 = blockIdx.x * 64;
    for (int i = t; i < 64 * (K / 4); i += 256) {
        int row = i / (K / 4), seg = i % (K / 4);
        int node = n0 + row;
        float4 v = {0, 0, 0, 0};
        if (node < n) v = *(const float4*)&Xf[(size_t)node * K + seg * 4];
        short4v o;
        o.x = (short)f2bf(v.x); o.y = (short)f2bf(v.y);
        o.z = (short)f2bf(v.z); o.w = (short)f2bf(v.w);
        *(short4v*)&Asd[row][seg * 4] = o;
    }
    for (int i = t; i < K * 16; i += 256) {
        int k = i >> 4, ng = i & 15;
        float4 v = *(const float4*)&W[(size_t)k * 64 + ng * 4];
        Bsd[ng * 4 + 0][k] = (short)f2bf(v.x);
        Bsd[ng * 4 + 1][k] = (short)f2bf(v.y);
        Bsd[ng * 4 + 2][k] = (short)f2bf(v.z);
        Bsd[ng * 4 + 3][k] = (short)f2bf(v.w);
    }
    __syncthreads();
    int wv = t >> 6, lane = t & 63;
    int m = lane & 15, quad = lane >> 4;
    int rowbase = wv * 16;
    f32x4 acc0 = {0,0,0,0}, acc1 = {0,0,0,0}, acc2 = {0,0,0,0}, acc3 = {0,0,0,0};
#pragma unroll
    for (int kb = 0; kb < K / 32; ++kb) {
        bf16x8 af = *(const bf16x8*)&Asd[rowbase + m][kb * 32 + quad * 8];
        bf16x8 b0 = *(const bf16x8*)&Bsd[ 0 + m][kb * 32 + quad * 8];
        bf16x8 b1 = *(const bf16x8*)&Bsd[16 + m][kb * 32 + quad * 8];
        bf16x8 b2 = *(const bf16x8*)&Bsd[32 + m][kb * 32 + quad * 8];
        bf16x8 b3 = *(const bf16x8*)&Bsd[48 + m][kb * 32 + quad * 8];
        acc0 = __builtin_amdgcn_mfma_f32_16x16x32_bf16(af, b0, acc0, 0, 0, 0);
        acc1 = __builtin_amdgcn_mfma_f32_16x16x32_bf16(af, b1, acc1, 0, 0, 0);
        acc2 = __builtin_amdgcn_mfma_f32_16x16x32_bf16(af, b2, acc2, 0, 0, 0);
        acc3 = __builtin_amdgcn_mfma_f32_16x16x32_bf16(af, b3, acc3, 0, 0, 0);
    }
    f32x4 accs[4] = {acc0, acc1, acc2, acc3};
#pragma unroll
    for (int r = 0; r < 4; ++r) {
        int node = n0 + rowbase + quad * 4 + r;
        if (node < n) {
            float sc = inv[node];
#pragma unroll
            for (int s = 0; s < 4; ++s)
                out[(size_t)node * 64 + s * 16 + m] = f2bf(accs[s][r] * sc);
        }
    }
}

// -------------------------- FUSED: aggregate(h1) + ReLU + (h@W2)*inv -> B ---
// 512 threads; single-pass gather: 8 waves x 8 octets = 64 nodes.
// MFMA phase: wave w -> row-tile (w&3), col-half (w>>2) of the 64x64 output.
__global__ __launch_bounds__(512) void agg_gemm2_kernel(
        const unsigned* __restrict__ rowptr, const unsigned* __restrict__ csr_src,
        const unsigned short* __restrict__ hs, const float* __restrict__ inv,
        const float* __restrict__ bias, const float* __restrict__ W,
        unsigned short* __restrict__ out, int n) {
    constexpr int K = HID_C;   // 64
    __shared__ __align__(16) short Asd[64][K + 8];
    __shared__ __align__(16) short Bsd[64][K + 8];
    int t = threadIdx.x;
    int n0 = blockIdx.x * 64;
    int lane = t & 63, w = t >> 6;
    int oct = lane >> 3, cl = lane & 7;
    const uint4* hsrow = (const uint4*)hs;
    // stage W2^T -> Bsd
    for (int i = t; i < K * 16; i += 512) {
        int k = i >> 4, ng = i & 15;
        float4 v = *(const float4*)&W[(size_t)k * 64 + ng * 4];
        Bsd[ng * 4 + 0][k] = (short)f2bf(v.x);
        Bsd[ng * 4 + 1][k] = (short)f2bf(v.y);
        Bsd[ng * 4 + 2][k] = (short)f2bf(v.z);
        Bsd[ng * 4 + 3][k] = (short)f2bf(v.w);
    }
    // phase 1: aggregate + ReLU -> Asd (single pass, node nl = w*8+oct)
    float4 bv0 = *(const float4*)&bias[cl * 8];
    float4 bv1 = *(const float4*)&bias[cl * 8 + 4];
    {
        int nl = w * 8 + oct;
        int node = n0 + nl;
        float r0 = 0.f, r1 = 0.f, r2 = 0.f, r3 = 0.f;
        float r4 = 0.f, r5 = 0.f, r6 = 0.f, r7 = 0.f;
        if (node < n) {
            float a0 = 0.f, a1 = 0.f, a2 = 0.f, a3 = 0.f;
            float a4 = 0.f, a5 = 0.f, a6 = 0.f, a7 = 0.f;
            agg_sums(rowptr, csr_src, hsrow, node, cl, a0, a1, a2, a3, a4, a5, a6, a7);
            uint4 sv = hsrow[(size_t)node * 8 + cl];
            float s = inv[node];
            r0 = fmaxf(s * (a0 + __uint_as_float(sv.x << 16))         + bv0.x, 0.f);
            r1 = fmaxf(s * (a1 + __uint_as_float(sv.x & 0xFFFF0000u)) + bv0.y, 0.f);
            r2 = fmaxf(s * (a2 + __uint_as_float(sv.y << 16))         + bv0.z, 0.f);
            r3 = fmaxf(s * (a3 + __uint_as_float(sv.y & 0xFFFF0000u)) + bv0.w, 0.f);
            r4 = fmaxf(s * (a4 + __uint_as_float(sv.z << 16))         + bv1.x, 0.f);
            r5 = fmaxf(s * (a5 + __uint_as_float(sv.z & 0xFFFF0000u)) + bv1.y, 0.f);
            r6 = fmaxf(s * (a6 + __uint_as_float(sv.w << 16))         + bv1.z, 0.f);
            r7 = fmaxf(s * (a7 + __uint_as_float(sv.w & 0xFFFF0000u)) + bv1.w, 0.f);
        }
        uint4 o;
        o.x = (unsigned)f2bf(r0) | ((unsigned)f2bf(r1) << 16);
        o.y = (unsigned)f2bf(r2) | ((unsigned)f2bf(r3) << 16);
        o.z = (unsigned)f2bf(r4) | ((unsigned)f2bf(r5) << 16);
        o.w = (unsigned)f2bf(r6) | ((unsigned)f2bf(r7) << 16);
        *(uint4*)&Asd[nl][cl * 8] = o;
    }
    __syncthreads();
    // phase 2: K=64 MFMA GEMM from LDS; wave w -> rows (w&3)*16, cols (w>>2)*32
    int m = lane & 15, quad = lane >> 4;
    int rowbase = (w & 3) * 16;
    int ch = w >> 2;   // column half: 0 or 1
    f32x4 acc0 = {0,0,0,0}, acc1 = {0,0,0,0};
#pragma unroll
    for (int kb = 0; kb < K / 32; ++kb) {
        bf16x8 af = *(const bf16x8*)&Asd[rowbase + m][kb * 32 + quad * 8];
        bf16x8 b0 = *(const bf16x8*)&Bsd[ch * 32 +  0 + m][kb * 32 + quad * 8];
        bf16x8 b1 = *(const bf16x8*)&Bsd[ch * 32 + 16 + m][kb * 32 + quad * 8];
        acc0 = __builtin_amdgcn_mfma_f32_16x16x32_bf16(af, b0, acc0, 0, 0, 0);
        acc1 = __builtin_amdgcn_mfma_f32_16x16x32_bf16(af, b1, acc1, 0, 0, 0);
    }
    f32x4 accs[2] = {acc0, acc1};
#pragma unroll
    for (int r = 0; r < 4; ++r) {
        int node = n0 + rowbase + quad * 4 + r;
        if (node < n) {
            float sc = inv[node];
#pragma unroll
            for (int s = 0; s < 2; ++s)
                out[(size_t)node * 64 + ch * 32 + s * 16 + m] = f2bf(accs[s][r] * sc);
        }
    }
}

// ------------------- FUSED: aggregate(h2) + ReLU + classifier @Wf -> out ----
// 512 threads, single-pass gather. MFMA classifier: waves 0-3 -> col-tiles
// 0,1; waves 4-7 -> col-tile 2.
__global__ __launch_bounds__(512) void agg_final_kernel(
        const unsigned* __restrict__ rowptr, const unsigned* __restrict__ csr_src,
        const unsigned short* __restrict__ hs, const float* __restrict__ inv,
        const float* __restrict__ bias, const float* __restrict__ Wf,
        const float* __restrict__ bfv, float* __restrict__ out, int n) {
    constexpr int K = HID_C;         // 64
    constexpr int J = NUM_CLASSES;   // 40
    __shared__ __align__(16) short Asd[64][K + 8];
    __shared__ __align__(16) short Bwf[48][K + 8];
    int t = threadIdx.x;
    int n0 = blockIdx.x * 64;
    int lane = t & 63, w = t >> 6;
    int oct = lane >> 3, cl = lane & 7;
    const uint4* hsrow = (const uint4*)hs;
    // stage Wf^T -> Bwf (class-major, k-contiguous); zero pad rows 40..47
    for (int i = t; i < 48 * K; i += 512) {
        int j = i >> 6, k = i & 63;
        Bwf[j][k] = (j < J) ? (short)f2bf(Wf[(size_t)k * J + j]) : (short)0;
    }
    // phase 1: aggregate + ReLU -> Asd (bf16), single pass
    float4 bv0 = *(const float4*)&bias[cl * 8];
    float4 bv1 = *(const float4*)&bias[cl * 8 + 4];
    {
        int nl = w * 8 + oct;
        int node = n0 + nl;
        float r0 = 0.f, r1 = 0.f, r2 = 0.f, r3 = 0.f;
        float r4 = 0.f, r5 = 0.f, r6 = 0.f, r7 = 0.f;
        if (node < n) {
            float a0 = 0.f, a1 = 0.f, a2 = 0.f, a3 = 0.f;
            float a4 = 0.f, a5 = 0.f, a6 = 0.f, a7 = 0.f;
            agg_sums(rowptr, csr_src, hsrow, node, cl, a0, a1, a2, a3, a4, a5, a6, a7);
            uint4 sv = hsrow[(size_t)node * 8 + cl];
            float s = inv[node];
            r0 = fmaxf(s * (a0 + __uint_as_float(sv.x << 16))         + bv0.x, 0.f);
            r1 = fmaxf(s * (a1 + __uint_as_float(sv.x & 0xFFFF0000u)) + bv0.y, 0.f);
            r2 = fmaxf(s * (a2 + __uint_as_float(sv.y << 16))         + bv0.z, 0.f);
            r3 = fmaxf(s * (a3 + __uint_as_float(sv.y & 0xFFFF0000u)) + bv0.w, 0.f);
            r4 = fmaxf(s * (a4 + __uint_as_float(sv.z << 16))         + bv1.x, 0.f);
            r5 = fmaxf(s * (a5 + __uint_as_float(sv.z & 0xFFFF0000u)) + bv1.y, 0.f);
            r6 = fmaxf(s * (a6 + __uint_as_float(sv.w << 16))         + bv1.z, 0.f);
            r7 = fmaxf(s * (a7 + __uint_as_float(sv.w & 0xFFFF0000u)) + bv1.w, 0.f);
        }
        uint4 o;
        o.x = (unsigned)f2bf(r0) | ((unsigned)f2bf(r1) << 16);
        o.y = (unsigned)f2bf(r2) | ((unsigned)f2bf(r3) << 16);
        o.z = (unsigned)f2bf(r4) | ((unsigned)f2bf(r5) << 16);
        o.w = (unsigned)f2bf(r6) | ((unsigned)f2bf(r7) << 16);
        *(uint4*)&Asd[nl][cl * 8] = o;
    }
    __syncthreads();
    // phase 2: MFMA classifier; waves 0-3: col-tiles 0,1; waves 4-7: tile 2
    int m = lane & 15, quad = lane >> 4;
    int rowbase = (w & 3) * 16;
    if (w < 4) {
        f32x4 acc0 = {0,0,0,0}, acc1 = {0,0,0,0};
#pragma unroll
        for (int kb = 0; kb < K / 32; ++kb) {
            bf16x8 af = *(const bf16x8*)&Asd[rowbase + m][kb * 32 + quad * 8];
            bf16x8 b0 = *(const bf16x8*)&Bwf[ 0 + m][kb * 32 + quad * 8];
            bf16x8 b1 = *(const bf16x8*)&Bwf[16 + m][kb * 32 + quad * 8];
            acc0 = __builtin_amdgcn_mfma_f32_16x16x32_bf16(af, b0, acc0, 0, 0, 0);
            acc1 = __builtin_amdgcn_mfma_f32_16x16x32_bf16(af, b1, acc1, 0, 0, 0);
        }
        f32x4 accs[2] = {acc0, acc1};
#pragma unroll
        for (int r = 0; r < 4; ++r) {
            int node = n0 + rowbase + quad * 4 + r;
            if (node < n) {
#pragma unroll
                for (int s = 0; s < 2; ++s) {
                    int col = s * 16 + m;
                    out[(size_t)node * J + col] = accs[s][r] + bfv[col];
                }
            }
        }
    } else {
        f32x4 acc2 = {0,0,0,0};
#pragma unroll
        for (int kb = 0; kb < K / 32; ++kb) {
            bf16x8 af = *(const bf16x8*)&Asd[rowbase + m][kb * 32 + quad * 8];
            bf16x8 b2 = *(const bf16x8*)&Bwf[32 + m][kb * 32 + quad * 8];
            acc2 = __builtin_amdgcn_mfma_f32_16x16x32_bf16(af, b2, acc2, 0, 0, 0);
        }
#pragma unroll
        for (int r = 0; r < 4; ++r) {
            int node = n0 + rowbase + quad * 4 + r;
            if (node < n) {
                int col = 32 + m;
                if (col < J)
                    out[(size_t)node * J + col] = acc2[r] + bfv[col];
            }
        }
    }
}

// ---------------------------------------------------------------- launch ----
extern "C" void kernel_launch(void* const* d_in, const int* in_sizes, int n_in,
                              void* d_out, int out_size, void* d_ws, size_t ws_size,
                              hipStream_t stream) {
    const float* x  = (const float*)d_in[0];
    const int*   ei = (const int*)d_in[1];
    const float* W1 = (const float*)d_in[2];
    const float* b1 = (const float*)d_in[3];
    const float* W2 = (const float*)d_in[4];
    const float* b2 = (const float*)d_in[5];
    const float* Wf = (const float*)d_in[6];
    const float* bf = (const float*)d_in[7];
    float* out = (float*)d_out;

    const int* src = ei;            // edge_index[0, :]
    const int* dst = ei + N_EDGES;  // edge_index[1, :]

    // Workspace layout (bytes):
    // rowptr: [0, 400064) | inv: [400064, 800064) | gcur: [800064, 800896)
    // csr_src: [801792, 7201792)
    // A (bf16, 12.8MB): [7201792, 20001792) | B (bf16): [20001792, 32801792)
    // stage (7.23 MB) aliases A: dead before gemm1 writes A (stream-ordered).
    char* ws = (char*)d_ws;
    unsigned* rowptr  = (unsigned*)(ws + 0);
    float*    inv     = (float*)   (ws + 400064);
    unsigned* gcur    = (unsigned*)(ws + 800064);
    unsigned* csr_src = (unsigned*)(ws + 801792);
    unsigned short* A = (unsigned short*)(ws + 7201792);
    unsigned short* B = (unsigned short*)(ws + 20001792);
    unsigned* stage   = (unsigned*)A;

    // ---- CSR build (per-call; no state survives between calls)
    hipMemsetAsync(gcur, 0, NBUCK * sizeof(unsigned), stream);
    fill_stage_kernel<<<FS_BLKS, FS_T, 0, stream>>>(src, dst, gcur, stage);
    fill_final_kernel<<<NBUCK, 512, 0, stream>>>(gcur, stage, rowptr, inv, csr_src);

    // ---- Layer 1 GEMM: A = (x@W1)*inv (bf16)
    gemm_mfma_kernel<<<(N_NODES + 63) / 64, 256, 0, stream>>>(x, W1, inv, A, N_NODES);

    // ---- Fused: h1 = ReLU(agg(A)+b1); B = (h1@W2)*inv
    agg_gemm2_kernel<<<(N_NODES + 63) / 64, 512, 0, stream>>>(
        rowptr, csr_src, A, inv, b1, W2, B, N_NODES);

    // ---- Fused: h2 = ReLU(agg(B)+b2); out = h2@Wf + bf
    agg_final_kernel<<<(N_NODES + 63) / 64, 512, 0, stream>>>(
        rowptr, csr_src, B, inv, b2, Wf, bf, out, N_NODES);
}

// Round 12
// 220.263 us; speedup vs baseline: 1.0751x; 1.0230x over previous
//
#include <hip/hip_runtime.h>

// Problem constants (fixed by the reference).
constexpr int N_NODES = 100000;
constexpr int N_EDGES = 1600000;
constexpr int IN_C  = 128;
constexpr int HID_C = 64;   // == OUT_C
constexpr int NUM_CLASSES = 40;

// Bucketed CSR build: 512-node buckets, fixed-capacity staging.
constexpr int BSH = 9;
constexpr int BUCK_N = 1 << BSH;                          // 512
constexpr int NBUCK = (N_NODES + BUCK_N - 1) >> BSH;      // 196
constexpr int BCAP = 9216;      // per-bucket cap; mean 8192, sd~90 (11σ margin)
constexpr int FS_EPT = 16;
constexpr int FS_T = 256;
constexpr int FS_CHUNK = FS_EPT * FS_T;                   // 4096
constexpr int FS_BLKS = (N_EDGES + FS_CHUNK - 1) / FS_CHUNK;  // 391

typedef __attribute__((ext_vector_type(8))) short bf16x8;
typedef __attribute__((ext_vector_type(4))) short short4v;
typedef __attribute__((ext_vector_type(4))) float f32x4;

// bf16 storage helpers (fp32 math everywhere; bf16 only at rest).
__device__ __forceinline__ unsigned short f2bf(float f) {
    unsigned u = __float_as_uint(f);
    return (unsigned short)((u + 0x7FFFu + ((u >> 16) & 1u)) >> 16);   // RNE
}
__device__ __forceinline__ float bf2f(unsigned short h) {
    return __uint_as_float((unsigned)h << 16);
}

// ---------------------------------------------------------------- CSR -------
// Group edges into fixed per-bucket staging regions, packed (src<<9)|dst_lo.
__global__ __launch_bounds__(FS_T) void fill_stage_kernel(
        const int* __restrict__ src, const int* __restrict__ dst,
        unsigned* __restrict__ gcur, unsigned* __restrict__ stage) {
    __shared__ unsigned hist[NBUCK];
    __shared__ unsigned rbase[NBUCK];
    int t = threadIdx.x;
    for (int i = t; i < NBUCK; i += FS_T) hist[i] = 0u;
    __syncthreads();
    int e0 = blockIdx.x * FS_CHUNK + t;
    unsigned pay[FS_EPT];
    unsigned br[FS_EPT];   // (bucket<<16)|rank
#pragma unroll
    for (int i = 0; i < FS_EPT; ++i) {
        int e = e0 + i * FS_T;
        br[i] = 0xFFFFFFFFu; pay[i] = 0u;
        if (e < N_EDGES) {
            unsigned d = (unsigned)dst[e];
            unsigned s = (unsigned)src[e];
            unsigned b = d >> BSH;
            unsigned r = atomicAdd(&hist[b], 1u);   // rank < 4096
            pay[i] = (s << BSH) | (d & (BUCK_N - 1u));
            br[i]  = (b << 16) | r;
        }
    }
    __syncthreads();
    for (int i = t; i < NBUCK; i += FS_T) {
        unsigned c = hist[i];
        rbase[i] = c ? ((unsigned)i * BCAP + atomicAdd(&gcur[i], c)) : 0u;
    }
    __syncthreads();
#pragma unroll
    for (int i = 0; i < FS_EPT; ++i) {
        if (br[i] != 0xFFFFFFFFu) {
            unsigned bb = br[i] >> 16;
            unsigned idx = rbase[bb] + (br[i] & 0xFFFFu);
            if (idx < (bb + 1u) * BCAP) stage[idx] = pay[i];   // safety clamp
        }
    }
}

// One block per bucket; 512 threads. Computes its own bucket base by
// scanning gcur (replaces the serializing 1-block scan_buckets dispatch).
__global__ __launch_bounds__(512) void fill_final_kernel(
        const unsigned* __restrict__ gcur,
        const unsigned* __restrict__ stage, unsigned* __restrict__ rowptr,
        float* __restrict__ inv, unsigned* __restrict__ csr_src) {
    __shared__ unsigned cur[BUCK_N];
    __shared__ unsigned ps[512];
    __shared__ unsigned buf[BCAP];
    int b = blockIdx.x, t = threadIdx.x;
    int lo = b << BSH;
    int nn = min(BUCK_N, N_NODES - lo);
    unsigned gv = (t < NBUCK) ? gcur[t] : 0u;
    ps[t] = gv;
    __syncthreads();
    for (int off = 1; off < 256; off <<= 1) {
        unsigned u = (t >= off) ? ps[t - off] : 0u;
        __syncthreads();
        ps[t] += u;
        __syncthreads();
    }
    unsigned base = ps[b] - gcur[b];          // exclusive prefix at b
    if (b == NBUCK - 1 && t == 0) rowptr[N_NODES] = ps[NBUCK - 1];
    unsigned c = min(gcur[b], (unsigned)BCAP);
    const unsigned* st = stage + (size_t)b * BCAP;
    cur[t] = 0u;
    __syncthreads();
    for (int i = t; i < (int)c; i += 512) atomicAdd(&cur[st[i] & (BUCK_N - 1u)], 1u);
    __syncthreads();
    unsigned d = cur[t];                      // in-bucket degree of node lo+t
    ps[t] = d;
    __syncthreads();
    for (int off = 1; off < 512; off <<= 1) {
        unsigned u = (t >= off) ? ps[t - off] : 0u;
        __syncthreads();
        ps[t] += u;
        __syncthreads();
    }
    unsigned off0 = ps[t] - d;   // exclusive prefix
    if (t < nn) {
        rowptr[lo + t] = base + off0;
        inv[lo + t] = rsqrtf((float)(d + 1u));
    }
    __syncthreads();
    cur[t] = off0;
    __syncthreads();
    for (int i = t; i < (int)c; i += 512) {
        unsigned v = st[i];
        unsigned pos = atomicAdd(&cur[v & (BUCK_N - 1u)], 1u);
        buf[pos] = v >> BSH;
    }
    __syncthreads();
    for (int i = t; i < (int)c; i += 512) csr_src[base + i] = buf[i];
}

// ----------------------------------------------- gather-aggregate helper ----
// Octet-per-node aggregation sums. Lane owns channels cl*8..cl*8+7; index
// load is octet-uniform -> broadcast. R10: reverted to the R8 rolled form
// (unroll 4). Ledger: R9's explicit depth-8 batch REGRESSED (+9.6 us); R8's
// wave-doubling gained only -7% -> gather is random-line service-bound
// (204.8 MB @ ~4.9 TB/s = structural floor for 128 B/edge).
__device__ __forceinline__ void agg_sums(
        const unsigned* __restrict__ rowptr, const unsigned* __restrict__ csr_src,
        const uint4* __restrict__ hsrow, int node, int cl,
        float& a0, float& a1, float& a2, float& a3,
        float& a4, float& a5, float& a6, float& a7) {
    unsigned beg = rowptr[node], end = rowptr[node + 1];
#pragma unroll 4
    for (unsigned e = beg; e < end; ++e) {
        unsigned s = csr_src[e];
        uint4 v = hsrow[(size_t)s * 8 + cl];
        a0 += __uint_as_float(v.x << 16);
        a1 += __uint_as_float(v.x & 0xFFFF0000u);
        a2 += __uint_as_float(v.y << 16);
        a3 += __uint_as_float(v.y & 0xFFFF0000u);
        a4 += __uint_as_float(v.z << 16);
        a5 += __uint_as_float(v.z & 0xFFFF0000u);
        a6 += __uint_as_float(v.w << 16);
        a7 += __uint_as_float(v.w & 0xFFFF0000u);
    }
}

// ------------------------------------------- MFMA GEMM (X@W)*inv -> bf16 ----
// Layer-1 only (K=128, fp32 input). Verified layouts (§3).
// R11: 512 threads (was 256). This kernel is HBM-bound (64 MB traffic) but
// ran at 16 waves/CU (4 blocks x 4 waves, 50% of cap). 8 waves/block at the
// same 34.8 KB LDS -> 4 blocks x 8 waves = 32 waves = 100% of wave cap.
// MFMA phase uses the verified w-split (same as agg_gemm2 phase 2):
// wave w -> rows (w&3)*16, col-half (w>>2).
__global__ __launch_bounds__(512) void gemm_mfma_kernel(
        const float* __restrict__ Xf, const float* __restrict__ W,
        const float* __restrict__ inv, unsigned short* __restrict__ out, int n) {
    constexpr int K = IN_C;
    __shared__ __align__(16) short Asd[64][K + 8];
    __shared__ __align__(16) short Bsd[64][K + 8];
    int t = threadIdx.x;
    int n0 = blockIdx.x * 64;
    for (int i = t; i < 64 * (K / 4); i += 512) {
        int row = i / (K / 4), seg = i % (K / 4);
        int node = n0 + row;
        float4 v = {0, 0, 0, 0};
        if (node < n) v = *(const float4*)&Xf[(size_t)node * K + seg * 4];
        short4v o;
        o.x = (short)f2bf(v.x); o.y = (short)f2bf(v.y);
        o.z = (short)f2bf(v.z); o.w = (short)f2bf(v.w);
        *(short4v*)&Asd[row][seg * 4] = o;
    }
    for (int i = t; i < K * 16; i += 512) {
        int k = i >> 4, ng = i & 15;
        float4 v = *(const float4*)&W[(size_t)k * 64 + ng * 4];
        Bsd[ng * 4 + 0][k] = (short)f2bf(v.x);
        Bsd[ng * 4 + 1][k] = (short)f2bf(v.y);
        Bsd[ng * 4 + 2][k] = (short)f2bf(v.z);
        Bsd[ng * 4 + 3][k] = (short)f2bf(v.w);
    }
    __syncthreads();
    int w = t >> 6, lane = t & 63;
    int m = lane & 15, quad = lane >> 4;
    int rowbase = (w & 3) * 16;
    int ch = w >> 2;   // column half: 0 or 1
    f32x4 acc0 = {0,0,0,0}, acc1 = {0,0,0,0};
#pragma unroll
    for (int kb = 0; kb < K / 32; ++kb) {
        bf16x8 af = *(const bf16x8*)&Asd[rowbase + m][kb * 32 + quad * 8];
        bf16x8 b0 = *(const bf16x8*)&Bsd[ch * 32 +  0 + m][kb * 32 + quad * 8];
        bf16x8 b1 = *(const bf16x8*)&Bsd[ch * 32 + 16 + m][kb * 32 + quad * 8];
        acc0 = __builtin_amdgcn_mfma_f32_16x16x32_bf16(af, b0, acc0, 0, 0, 0);
        acc1 = __builtin_amdgcn_mfma_f32_16x16x32_bf16(af, b1, acc1, 0, 0, 0);
    }
    f32x4 accs[2] = {acc0, acc1};
#pragma unroll
    for (int r = 0; r < 4; ++r) {
        int node = n0 + rowbase + quad * 4 + r;
        if (node < n) {
            float sc = inv[node];
#pragma unroll
            for (int s = 0; s < 2; ++s)
                out[(size_t)node * 64 + ch * 32 + s * 16 + m] = f2bf(accs[s][r] * sc);
        }
    }
}

// -------------------------- FUSED: aggregate(h1) + ReLU + (h@W2)*inv -> B ---
// 512 threads; single-pass gather: 8 waves x 8 octets = 64 nodes.
// MFMA phase: wave w -> row-tile (w&3), col-half (w>>2) of the 64x64 output.
__global__ __launch_bounds__(512) void agg_gemm2_kernel(
        const unsigned* __restrict__ rowptr, const unsigned* __restrict__ csr_src,
        const unsigned short* __restrict__ hs, const float* __restrict__ inv,
        const float* __restrict__ bias, const float* __restrict__ W,
        unsigned short* __restrict__ out, int n) {
    constexpr int K = HID_C;   // 64
    __shared__ __align__(16) short Asd[64][K + 8];
    __shared__ __align__(16) short Bsd[64][K + 8];
    int t = threadIdx.x;
    int n0 = blockIdx.x * 64;
    int lane = t & 63, w = t >> 6;
    int oct = lane >> 3, cl = lane & 7;
    const uint4* hsrow = (const uint4*)hs;
    // stage W2^T -> Bsd
    for (int i = t; i < K * 16; i += 512) {
        int k = i >> 4, ng = i & 15;
        float4 v = *(const float4*)&W[(size_t)k * 64 + ng * 4];
        Bsd[ng * 4 + 0][k] = (short)f2bf(v.x);
        Bsd[ng * 4 + 1][k] = (short)f2bf(v.y);
        Bsd[ng * 4 + 2][k] = (short)f2bf(v.z);
        Bsd[ng * 4 + 3][k] = (short)f2bf(v.w);
    }
    // phase 1: aggregate + ReLU -> Asd (single pass, node nl = w*8+oct)
    float4 bv0 = *(const float4*)&bias[cl * 8];
    float4 bv1 = *(const float4*)&bias[cl * 8 + 4];
    {
        int nl = w * 8 + oct;
        int node = n0 + nl;
        float r0 = 0.f, r1 = 0.f, r2 = 0.f, r3 = 0.f;
        float r4 = 0.f, r5 = 0.f, r6 = 0.f, r7 = 0.f;
        if (node < n) {
            float a0 = 0.f, a1 = 0.f, a2 = 0.f, a3 = 0.f;
            float a4 = 0.f, a5 = 0.f, a6 = 0.f, a7 = 0.f;
            agg_sums(rowptr, csr_src, hsrow, node, cl, a0, a1, a2, a3, a4, a5, a6, a7);
            uint4 sv = hsrow[(size_t)node * 8 + cl];
            float s = inv[node];
            r0 = fmaxf(s * (a0 + __uint_as_float(sv.x << 16))         + bv0.x, 0.f);
            r1 = fmaxf(s * (a1 + __uint_as_float(sv.x & 0xFFFF0000u)) + bv0.y, 0.f);
            r2 = fmaxf(s * (a2 + __uint_as_float(sv.y << 16))         + bv0.z, 0.f);
            r3 = fmaxf(s * (a3 + __uint_as_float(sv.y & 0xFFFF0000u)) + bv0.w, 0.f);
            r4 = fmaxf(s * (a4 + __uint_as_float(sv.z << 16))         + bv1.x, 0.f);
            r5 = fmaxf(s * (a5 + __uint_as_float(sv.z & 0xFFFF0000u)) + bv1.y, 0.f);
            r6 = fmaxf(s * (a6 + __uint_as_float(sv.w << 16))         + bv1.z, 0.f);
            r7 = fmaxf(s * (a7 + __uint_as_float(sv.w & 0xFFFF0000u)) + bv1.w, 0.f);
        }
        uint4 o;
        o.x = (unsigned)f2bf(r0) | ((unsigned)f2bf(r1) << 16);
        o.y = (unsigned)f2bf(r2) | ((unsigned)f2bf(r3) << 16);
        o.z = (unsigned)f2bf(r4) | ((unsigned)f2bf(r5) << 16);
        o.w = (unsigned)f2bf(r6) | ((unsigned)f2bf(r7) << 16);
        *(uint4*)&Asd[nl][cl * 8] = o;
    }
    __syncthreads();
    // phase 2: K=64 MFMA GEMM from LDS; wave w -> rows (w&3)*16, cols (w>>2)*32
    int m = lane & 15, quad = lane >> 4;
    int rowbase = (w & 3) * 16;
    int ch = w >> 2;   // column half: 0 or 1
    f32x4 acc0 = {0,0,0,0}, acc1 = {0,0,0,0};
#pragma unroll
    for (int kb = 0; kb < K / 32; ++kb) {
        bf16x8 af = *(const bf16x8*)&Asd[rowbase + m][kb * 32 + quad * 8];
        bf16x8 b0 = *(const bf16x8*)&Bsd[ch * 32 +  0 + m][kb * 32 + quad * 8];
        bf16x8 b1 = *(const bf16x8*)&Bsd[ch * 32 + 16 + m][kb * 32 + quad * 8];
        acc0 = __builtin_amdgcn_mfma_f32_16x16x32_bf16(af, b0, acc0, 0, 0, 0);
        acc1 = __builtin_amdgcn_mfma_f32_16x16x32_bf16(af, b1, acc1, 0, 0, 0);
    }
    f32x4 accs[2] = {acc0, acc1};
#pragma unroll
    for (int r = 0; r < 4; ++r) {
        int node = n0 + rowbase + quad * 4 + r;
        if (node < n) {
            float sc = inv[node];
#pragma unroll
            for (int s = 0; s < 2; ++s)
                out[(size_t)node * 64 + ch * 32 + s * 16 + m] = f2bf(accs[s][r] * sc);
        }
    }
}

// ------------------- FUSED: aggregate(h2) + ReLU + classifier @Wf -> out ----
// 512 threads, single-pass gather. MFMA classifier: waves 0-3 -> col-tiles
// 0,1; waves 4-7 -> col-tile 2.
__global__ __launch_bounds__(512) void agg_final_kernel(
        const unsigned* __restrict__ rowptr, const unsigned* __restrict__ csr_src,
        const unsigned short* __restrict__ hs, const float* __restrict__ inv,
        const float* __restrict__ bias, const float* __restrict__ Wf,
        const float* __restrict__ bfv, float* __restrict__ out, int n) {
    constexpr int K = HID_C;         // 64
    constexpr int J = NUM_CLASSES;   // 40
    __shared__ __align__(16) short Asd[64][K + 8];
    __shared__ __align__(16) short Bwf[48][K + 8];
    int t = threadIdx.x;
    int n0 = blockIdx.x * 64;
    int lane = t & 63, w = t >> 6;
    int oct = lane >> 3, cl = lane & 7;
    const uint4* hsrow = (const uint4*)hs;
    // stage Wf^T -> Bwf (class-major, k-contiguous); zero pad rows 40..47
    for (int i = t; i < 48 * K; i += 512) {
        int j = i >> 6, k = i & 63;
        Bwf[j][k] = (j < J) ? (short)f2bf(Wf[(size_t)k * J + j]) : (short)0;
    }
    // phase 1: aggregate + ReLU -> Asd (bf16), single pass
    float4 bv0 = *(const float4*)&bias[cl * 8];
    float4 bv1 = *(const float4*)&bias[cl * 8 + 4];
    {
        int nl = w * 8 + oct;
        int node = n0 + nl;
        float r0 = 0.f, r1 = 0.f, r2 = 0.f, r3 = 0.f;
        float r4 = 0.f, r5 = 0.f, r6 = 0.f, r7 = 0.f;
        if (node < n) {
            float a0 = 0.f, a1 = 0.f, a2 = 0.f, a3 = 0.f;
            float a4 = 0.f, a5 = 0.f, a6 = 0.f, a7 = 0.f;
            agg_sums(rowptr, csr_src, hsrow, node, cl, a0, a1, a2, a3, a4, a5, a6, a7);
            uint4 sv = hsrow[(size_t)node * 8 + cl];
            float s = inv[node];
            r0 = fmaxf(s * (a0 + __uint_as_float(sv.x << 16))         + bv0.x, 0.f);
            r1 = fmaxf(s * (a1 + __uint_as_float(sv.x & 0xFFFF0000u)) + bv0.y, 0.f);
            r2 = fmaxf(s * (a2 + __uint_as_float(sv.y << 16))         + bv0.z, 0.f);
            r3 = fmaxf(s * (a3 + __uint_as_float(sv.y & 0xFFFF0000u)) + bv0.w, 0.f);
            r4 = fmaxf(s * (a4 + __uint_as_float(sv.z << 16))         + bv1.x, 0.f);
            r5 = fmaxf(s * (a5 + __uint_as_float(sv.z & 0xFFFF0000u)) + bv1.y, 0.f);
            r6 = fmaxf(s * (a6 + __uint_as_float(sv.w << 16))         + bv1.z, 0.f);
            r7 = fmaxf(s * (a7 + __uint_as_float(sv.w & 0xFFFF0000u)) + bv1.w, 0.f);
        }
        uint4 o;
        o.x = (unsigned)f2bf(r0) | ((unsigned)f2bf(r1) << 16);
        o.y = (unsigned)f2bf(r2) | ((unsigned)f2bf(r3) << 16);
        o.z = (unsigned)f2bf(r4) | ((unsigned)f2bf(r5) << 16);
        o.w = (unsigned)f2bf(r6) | ((unsigned)f2bf(r7) << 16);
        *(uint4*)&Asd[nl][cl * 8] = o;
    }
    __syncthreads();
    // phase 2: MFMA classifier; waves 0-3: col-tiles 0,1; waves 4-7: tile 2
    int m = lane & 15, quad = lane >> 4;
    int rowbase = (w & 3) * 16;
    if (w < 4) {
        f32x4 acc0 = {0,0,0,0}, acc1 = {0,0,0,0};
#pragma unroll
        for (int kb = 0; kb < K / 32; ++kb) {
            bf16x8 af = *(const bf16x8*)&Asd[rowbase + m][kb * 32 + quad * 8];
            bf16x8 b0 = *(const bf16x8*)&Bwf[ 0 + m][kb * 32 + quad * 8];
            bf16x8 b1 = *(const bf16x8*)&Bwf[16 + m][kb * 32 + quad * 8];
            acc0 = __builtin_amdgcn_mfma_f32_16x16x32_bf16(af, b0, acc0, 0, 0, 0);
            acc1 = __builtin_amdgcn_mfma_f32_16x16x32_bf16(af, b1, acc1, 0, 0, 0);
        }
        f32x4 accs[2] = {acc0, acc1};
#pragma unroll
        for (int r = 0; r < 4; ++r) {
            int node = n0 + rowbase + quad * 4 + r;
            if (node < n) {
#pragma unroll
                for (int s = 0; s < 2; ++s) {
                    int col = s * 16 + m;
                    out[(size_t)node * J + col] = accs[s][r] + bfv[col];
                }
            }
        }
    } else {
        f32x4 acc2 = {0,0,0,0};
#pragma unroll
        for (int kb = 0; kb < K / 32; ++kb) {
            bf16x8 af = *(const bf16x8*)&Asd[rowbase + m][kb * 32 + quad * 8];
            bf16x8 b2 = *(const bf16x8*)&Bwf[32 + m][kb * 32 + quad * 8];
            acc2 = __builtin_amdgcn_mfma_f32_16x16x32_bf16(af, b2, acc2, 0, 0, 0);
        }
#pragma unroll
        for (int r = 0; r < 4; ++r) {
            int node = n0 + rowbase + quad * 4 + r;
            if (node < n) {
                int col = 32 + m;
                if (col < J)
                    out[(size_t)node * J + col] = acc2[r] + bfv[col];
            }
        }
    }
}

// ---------------------------------------------------------------- launch ----
extern "C" void kernel_launch(void* const* d_in, const int* in_sizes, int n_in,
                              void* d_out, int out_size, void* d_ws, size_t ws_size,
                              hipStream_t stream) {
    const float* x  = (const float*)d_in[0];
    const int*   ei = (const int*)d_in[1];
    const float* W1 = (const float*)d_in[2];
    const float* b1 = (const float*)d_in[3];
    const float* W2 = (const float*)d_in[4];
    const float* b2 = (const float*)d_in[5];
    const float* Wf = (const float*)d_in[6];
    const float* bf = (const float*)d_in[7];
    float* out = (float*)d_out;

    const int* src = ei;            // edge_index[0, :]
    const int* dst = ei + N_EDGES;  // edge_index[1, :]

    // Workspace layout (bytes):
    // rowptr: [0, 400064) | inv: [400064, 800064) | gcur: [800064, 800896)
    // csr_src: [801792, 7201792)
    // A (bf16, 12.8MB): [7201792, 20001792) | B (bf16): [20001792, 32801792)
    // stage (7.23 MB) aliases A: dead before gemm1 writes A (stream-ordered).
    char* ws = (char*)d_ws;
    unsigned* rowptr  = (unsigned*)(ws + 0);
    float*    inv     = (float*)   (ws + 400064);
    unsigned* gcur    = (unsigned*)(ws + 800064);
    unsigned* csr_src = (unsigned*)(ws + 801792);
    unsigned short* A = (unsigned short*)(ws + 7201792);
    unsigned short* B = (unsigned short*)(ws + 20001792);
    unsigned* stage   = (unsigned*)A;

    // ---- CSR build (per-call; no state survives between calls)
    hipMemsetAsync(gcur, 0, NBUCK * sizeof(unsigned), stream);
    fill_stage_kernel<<<FS_BLKS, FS_T, 0, stream>>>(src, dst, gcur, stage);
    fill_final_kernel<<<NBUCK, 512, 0, stream>>>(gcur, stage, rowptr, inv, csr_src);

    // ---- Layer 1 GEMM: A = (x@W1)*inv (bf16)
    gemm_mfma_kernel<<<(N_NODES + 63) / 64, 512, 0, stream>>>(x, W1, inv, A, N_NODES);

    // ---- Fused: h1 = ReLU(agg(A)+b1); B = (h1@W2)*inv
    agg_gemm2_kernel<<<(N_NODES + 63) / 64, 512, 0, stream>>>(
        rowptr, csr_src, A, inv, b1, W2, B, N_NODES);

    // ---- Fused: h2 = ReLU(agg(B)+b2); out = h2@Wf + bf
    agg_final_kernel<<<(N_NODES + 63) / 64, 512, 0, stream>>>(
        rowptr, csr_src, B, inv, b2, Wf, bf, out, N_NODES);
}